// Round 4
// baseline (749.724 us; speedup 1.0000x reference)
//
#include <hip/hip_runtime.h>
#include <hip/hip_bf16.h>

#define NN 384
#define CIN 128
#define NH 4
#define CH 32
#define NPOS (NN * NN)      // 147456
#define INFB 1e9f
#define LOG2E 1.4426950408889634f
#define QSCALE 0.17677669529663687f   // 1/sqrt(32)
#define QSB (QSCALE * LOG2E)

typedef float f32x4 __attribute__((ext_vector_type(4)));
typedef short bf16x8 __attribute__((ext_vector_type(8)));
typedef short bf16x4 __attribute__((ext_vector_type(4)));

__device__ __forceinline__ float bf2f(unsigned short u) {
    return __uint_as_float(((unsigned int)u) << 16);
}
__device__ __forceinline__ unsigned short f2bf(float f) {
    unsigned int u = __float_as_uint(f);
    u += 0x7fffu + ((u >> 16) & 1u);
    return (unsigned short)(u >> 16);
}
__device__ __forceinline__ unsigned int pack2bf(float a, float b) {
    return (unsigned int)f2bf(a) | ((unsigned int)f2bf(b) << 16);
}

// ---------------------------------------------------------------------------
// Kernel 1: LayerNorm -> zn bf16. Pure register streaming, 32 lanes per row.
// ---------------------------------------------------------------------------
__global__ __launch_bounds__(256) void ln_kernel(
    const float* __restrict__ z, const float* __restrict__ lnw, const float* __restrict__ lnb,
    unsigned short* __restrict__ zn)
{
    const int t = threadIdx.x;
    const int l31 = t & 31;
    const f32x4 lw = *(const f32x4*)(lnw + l31 * 4);
    const f32x4 lb = *(const f32x4*)(lnb + l31 * 4);
    #pragma unroll
    for (int it = 0; it < 4; ++it) {
        long row = (long)blockIdx.x * 32 + it * 8 + (threadIdx.x >> 5);
        f32x4 v = *(const f32x4*)(z + row * CIN + l31 * 4);
        float s = v[0] + v[1] + v[2] + v[3];
        float q = v[0]*v[0] + v[1]*v[1] + v[2]*v[2] + v[3]*v[3];
        #pragma unroll
        for (int m2 = 1; m2 < 32; m2 <<= 1) { s += __shfl_xor(s, m2); q += __shfl_xor(q, m2); }
        float mu = s * (1.f / CIN);
        float rs = rsqrtf(q * (1.f / CIN) - mu * mu + 1e-5f);
        uint2 o;
        o.x = pack2bf((v[0]-mu)*rs*lw[0]+lb[0], (v[1]-mu)*rs*lw[1]+lb[1]);
        o.y = pack2bf((v[2]-mu)*rs*lw[2]+lb[2], (v[3]-mu)*rs*lw[3]+lb[3]);
        *(uint2*)(zn + row * CIN + l31 * 4) = o;
    }
    (void)t;
}

// ---------------------------------------------------------------------------
// Kernel 2: weight convert. wcat[0..3] = Wq*QSB,Wk,Wv,Wg transposed [n][k];
// wcat[4] = wtri*LOG2E zero-padded to 128 cols; wot = wo^T.
// ---------------------------------------------------------------------------
__global__ __launch_bounds__(256) void wconv_kernel(
    const float* __restrict__ wq, const float* __restrict__ wk, const float* __restrict__ wv,
    const float* __restrict__ wg, const float* __restrict__ wtri, const float* __restrict__ wo,
    unsigned short* __restrict__ wcat, unsigned short* __restrict__ wot)
{
    const int m = blockIdx.x, t = threadIdx.x;
    for (int idx = t; idx < CIN * CIN; idx += 256) {
        int n = idx >> 7, k = idx & 127;
        if (m < 4) {
            const float* W = (m == 0) ? wq : (m == 1) ? wk : (m == 2) ? wv : wg;
            float s = (m == 0) ? QSB : 1.0f;
            wcat[m * CIN * CIN + idx] = f2bf(W[k * CIN + n] * s);
        } else if (m == 4) {
            wcat[4 * CIN * CIN + idx] = (n < NH) ? f2bf(wtri[k * NH + n] * LOG2E) : (unsigned short)0;
        } else {
            wot[idx] = f2bf(wo[k * CIN + n]);
        }
    }
}

// ---------------------------------------------------------------------------
// Kernel 3: fused 5-matrix projection GEMM. A (zn tile) staged+frag'd ONCE,
// B restaged per matrix. mat4 = tri (only cols 0..3 stored).
// ---------------------------------------------------------------------------
__global__ __launch_bounds__(256, 2) void proj_kernel(
    const unsigned short* __restrict__ zn, const unsigned short* __restrict__ wcat,
    unsigned short* __restrict__ qb, unsigned short* __restrict__ kb,
    unsigned short* __restrict__ vb, unsigned short* __restrict__ gb,
    unsigned short* __restrict__ trib)
{
    __shared__ alignas(16) unsigned short lsA[128 * 128];
    __shared__ alignas(16) unsigned short lsB[128 * 128];
    const int t = threadIdx.x;
    const int mb = blockIdx.x;
    const int lane = t & 63, w = t >> 6, l15 = lane & 15, hig = lane >> 4;

    {   // stage A (swizzled)
        const unsigned short* Ag = zn + (long)mb * 16384;
        #pragma unroll
        for (int it = 0; it < 8; ++it) {
            int row = w * 32 + it * 4 + hig; int cb = l15 * 16;
            uint4 v = *(const uint4*)((const char*)Ag + row * 256 + cb);
            *(uint4*)((char*)lsA + row * 256 + (cb ^ ((row & 7) << 4))) = v;
        }
    }
    auto stageB = [&](int mat) {
        const unsigned short* Bg = wcat + mat * 16384;
        #pragma unroll
        for (int it = 0; it < 8; ++it) {
            int row = w * 32 + it * 4 + hig; int cb = l15 * 16;
            uint4 v = *(const uint4*)((const char*)Bg + row * 256 + cb);
            *(uint4*)((char*)lsB + row * 256 + (cb ^ ((row & 7) << 4))) = v;
        }
    };
    stageB(0);
    __syncthreads();

    const int wm = (w >> 1) * 64, wn = (w & 1) * 64;
    bf16x8 a[4][4];
    #pragma unroll
    for (int kk = 0; kk < 4; ++kk)
        #pragma unroll
        for (int mf = 0; mf < 4; ++mf) {
            int ra = wm + mf * 16 + l15;
            a[kk][mf] = *(const bf16x8*)((const char*)lsA + ra * 256 + ((kk * 64 + hig * 16) ^ ((ra & 7) << 4)));
        }

    for (int mat = 0;;) {
        f32x4 acc[4][4];
        #pragma unroll
        for (int i = 0; i < 4; ++i)
            #pragma unroll
            for (int j = 0; j < 4; ++j) acc[i][j] = (f32x4){0.f, 0.f, 0.f, 0.f};
        #pragma unroll
        for (int kk = 0; kk < 4; ++kk) {
            bf16x8 b[4];
            #pragma unroll
            for (int nf = 0; nf < 4; ++nf) {
                int rb = wn + nf * 16 + l15;
                b[nf] = *(const bf16x8*)((const char*)lsB + rb * 256 + ((kk * 64 + hig * 16) ^ ((rb & 7) << 4)));
            }
            #pragma unroll
            for (int mf = 0; mf < 4; ++mf)
                #pragma unroll
                for (int nf = 0; nf < 4; ++nf)
                    acc[mf][nf] = __builtin_amdgcn_mfma_f32_16x16x32_bf16(a[kk][mf], b[nf], acc[mf][nf], 0, 0, 0);
        }
        __syncthreads();                       // all waves done reading lsB
        if (mat < 4) stageB(mat + 1);          // overlap restage with stores

        if (mat < 4) {
            unsigned short* dst = (mat == 0) ? qb : (mat == 1) ? kb : (mat == 2) ? vb : gb;
            #pragma unroll
            for (int mf = 0; mf < 4; ++mf)
                #pragma unroll
                for (int nf = 0; nf < 4; ++nf)
                    #pragma unroll
                    for (int r = 0; r < 4; ++r) {
                        long pos = (long)mb * 128 + wm + mf * 16 + hig * 4 + r;
                        int n = wn + nf * 16 + l15;
                        float v = acc[mf][nf][r];
                        if (mat == 3) v = 1.f / (1.f + __expf(-v));
                        dst[pos * CIN + n] = f2bf(v);
                    }
        } else {
            if (wn == 0 && l15 < NH) {
                #pragma unroll
                for (int mf = 0; mf < 4; ++mf)
                    #pragma unroll
                    for (int r = 0; r < 4; ++r) {
                        long pos = (long)mb * 128 + wm + mf * 16 + hig * 4 + r;
                        trib[(long)l15 * NPOS + pos] = f2bf(acc[mf][0][r]);
                    }
            }
        }
        if (mat == 4) break;
        ++mat;
        __syncthreads();                       // lsB(mat) ready
    }
}

// ---------------------------------------------------------------------------
// Kernel 4: attention per (i,h). Swapped QK^T (q lane-local softmax),
// tri+bias as MFMA C-init, V-frags in registers, chunked per-wave P LDS,
// exp2-domain softmax, fused sigmoid-gate epilogue.
// ---------------------------------------------------------------------------
__global__ __launch_bounds__(256, 2) void attn_kernel(
    const unsigned short* __restrict__ qb, const unsigned short* __restrict__ kb,
    const unsigned short* __restrict__ vb, const unsigned short* __restrict__ gb,
    const unsigned short* __restrict__ trib, const float* __restrict__ mask,
    unsigned short* __restrict__ ogb)
{
    constexpr int KP = 40;    // K row pad: 80 B rows (16B-aligned, 2-way-free banks)
    constexpr int VP = 392;   // V^T row pad: 784 B rows
    __shared__ alignas(16) unsigned short Ks[NN * KP];        // 30720 B
    __shared__ alignas(16) unsigned short VTs[CH * VP];       // 25088 B
    __shared__ alignas(16) unsigned short Ps[4][2][16 * 64];  // 16384 B per-wave dbuf
    __shared__ float biasS[NN];

    const int t = threadIdx.x;
    const int bid = blockIdx.x;
    const int wg = (bid & 7) * 192 + (bid >> 3);   // bijective XCD swizzle (1536 % 8 == 0)
    const int i = wg >> 2, h = wg & 3;
    const long rowbase = (long)i * NN;

    {   // stage K (padded), V^T (padded transpose), bias (log2e-scaled)
        const unsigned int* ksrc = (const unsigned int*)kb + rowbase * 64 + h * 16;
        for (int idx = t; idx < NN * 16; idx += 256) {
            int row = idx >> 4, c2 = idx & 15;
            *(unsigned int*)&Ks[row * KP + c2 * 2] = ksrc[(long)row * 64 + c2];
        }
        for (int idx = t; idx < CH * NN; idx += 256) {
            int n = idx >> 5, c = idx & 31;
            VTs[c * VP + n] = vb[(rowbase + n) * CIN + h * CH + c];
        }
        for (int idx = t; idx < NN; idx += 256)
            biasS[idx] = (INFB * LOG2E) * (mask[rowbase + idx] - 1.f);
    }
    __syncthreads();

    const int lane = t & 63, w = t >> 6, l15 = lane & 15, hig = lane >> 4;

    // V fragments -> registers, once per block (B-operand: lane = out channel)
    bf16x8 bv[12][2];
    #pragma unroll
    for (int ks = 0; ks < 12; ++ks)
        #pragma unroll
        for (int hf = 0; hf < 2; ++hf) {
            int c = hf * 16 + l15;
            bv[ks][hf] = *(const bf16x8*)&VTs[c * VP + ks * 32 + hig * 8];
        }

    char* Pw = (char*)Ps[w];

    for (int mt = w; mt < NN / 16; mt += 4) {
        const int q0 = mt * 16;
        // Q fragment as B-operand: lane l15 = q-row
        const bf16x8 aq = *(const bf16x8*)(qb + (rowbase + q0 + l15) * CIN + h * CH + hig * 8);
        const unsigned short* trow = trib + (long)h * NPOS + (long)(q0 + l15) * NN + hig * 4;

        // QK^T with C-init = tri + mask-bias (all in exp2 domain)
        f32x4 acc[24];
        #pragma unroll
        for (int nf = 0; nf < 24; ++nf) {
            bf16x4 t4 = *(const bf16x4*)(trow + nf * 16);
            f32x4 ci;
            #pragma unroll
            for (int r = 0; r < 4; ++r)
                ci[r] = bf2f((unsigned short)t4[r]) + biasS[nf * 16 + hig * 4 + r];
            const int krow = nf * 16 + l15;
            const bf16x8 ak = *(const bf16x8*)&Ks[krow * KP + hig * 8];
            acc[nf] = __builtin_amdgcn_mfma_f32_16x16x32_bf16(ak, aq, ci, 0, 0, 0);
        }

        // softmax: row q = l15 is lane-local; combine hi-groups with 2 shuffles
        float mx = -3e38f;
        #pragma unroll
        for (int nf = 0; nf < 24; ++nf)
            #pragma unroll
            for (int r = 0; r < 4; ++r) mx = fmaxf(mx, acc[nf][r]);
        mx = fmaxf(mx, __shfl_xor(mx, 16));
        mx = fmaxf(mx, __shfl_xor(mx, 32));
        float sum = 0.f;
        #pragma unroll
        for (int nf = 0; nf < 24; ++nf)
            #pragma unroll
            for (int r = 0; r < 4; ++r) {
                float p = exp2f(acc[nf][r] - mx);
                acc[nf][r] = p; sum += p;
            }
        sum += __shfl_xor(sum, 16);
        sum += __shfl_xor(sum, 32);
        const float inv = 1.0f / sum;

        // PV: chunked P through per-wave swizzled LDS (dbuf), V from registers
        f32x4 o0 = {0.f,0.f,0.f,0.f}, o1 = {0.f,0.f,0.f,0.f};
        __builtin_amdgcn_s_setprio(1);
        #pragma unroll
        for (int ch = 0; ch < 6; ++ch) {
            char* Pb = Pw + (ch & 1) * 2048;
            #pragma unroll
            for (int nfl = 0; nfl < 4; ++nfl) {
                int nf = ch * 4 + nfl;
                uint2 wv;
                wv.x = pack2bf(acc[nf][0], acc[nf][1]);
                wv.y = pack2bf(acc[nf][2], acc[nf][3]);
                *(uint2*)(Pb + l15 * 128 + ((nfl * 32 + hig * 8) ^ ((l15 & 7) << 4))) = wv;
            }
            #pragma unroll
            for (int ksl = 0; ksl < 2; ++ksl) {
                int ks = ch * 2 + ksl;
                bf16x8 ap = *(const bf16x8*)(Pb + l15 * 128 + ((ksl * 64 + hig * 16) ^ ((l15 & 7) << 4)));
                o0 = __builtin_amdgcn_mfma_f32_16x16x32_bf16(ap, bv[ks][0], o0, 0, 0, 0);
                o1 = __builtin_amdgcn_mfma_f32_16x16x32_bf16(ap, bv[ks][1], o1, 0, 0, 0);
            }
        }
        __builtin_amdgcn_s_setprio(0);

        // epilogue: normalize (inv gathered per output q-row), gate, store
        #pragma unroll
        for (int r = 0; r < 4; ++r) {
            float iv = __shfl(inv, hig * 4 + r);
            long qrow = rowbase + q0 + hig * 4 + r;
            float g0 = bf2f(gb[qrow * CIN + h * CH + l15]);
            float g1 = bf2f(gb[qrow * CIN + h * CH + 16 + l15]);
            ogb[qrow * CIN + h * CH + l15]      = f2bf(o0[r] * iv * g0);
            ogb[qrow * CIN + h * CH + 16 + l15] = f2bf(o1[r] * iv * g1);
        }
    }
}

// ---------------------------------------------------------------------------
// Kernel 5: out = og @ wo^T (fp32 out)
// ---------------------------------------------------------------------------
__global__ __launch_bounds__(256, 2) void out_gemm_kernel(
    const unsigned short* __restrict__ og, const unsigned short* __restrict__ wot,
    float* __restrict__ out)
{
    __shared__ alignas(16) unsigned short lsA[128 * 128];
    __shared__ alignas(16) unsigned short lsB[128 * 128];
    const int t = threadIdx.x;
    const int mb = blockIdx.x;
    const int lane = t & 63, w = t >> 6, l15 = lane & 15, hig = lane >> 4;

    {
        const unsigned short* Ag = og + (long)mb * 16384;
        #pragma unroll
        for (int it = 0; it < 8; ++it) {
            int row = w * 32 + it * 4 + hig; int cb = l15 * 16;
            uint4 va = *(const uint4*)((const char*)Ag + row * 256 + cb);
            uint4 vb4 = *(const uint4*)((const char*)wot + row * 256 + cb);
            int sw = cb ^ ((row & 7) << 4);
            *(uint4*)((char*)lsA + row * 256 + sw) = va;
            *(uint4*)((char*)lsB + row * 256 + sw) = vb4;
        }
    }
    __syncthreads();

    const int wm = (w >> 1) * 64, wn = (w & 1) * 64;
    f32x4 acc[4][4];
    #pragma unroll
    for (int i = 0; i < 4; ++i)
        #pragma unroll
        for (int j = 0; j < 4; ++j) acc[i][j] = (f32x4){0.f, 0.f, 0.f, 0.f};
    #pragma unroll
    for (int kk = 0; kk < 4; ++kk) {
        bf16x8 a[4], b[4];
        #pragma unroll
        for (int f = 0; f < 4; ++f) {
            int ra = wm + f * 16 + l15;
            int rb = wn + f * 16 + l15;
            int c = kk * 64 + hig * 16;
            a[f] = *(const bf16x8*)((const char*)lsA + ra * 256 + (c ^ ((ra & 7) << 4)));
            b[f] = *(const bf16x8*)((const char*)lsB + rb * 256 + (c ^ ((rb & 7) << 4)));
        }
        #pragma unroll
        for (int mf = 0; mf < 4; ++mf)
            #pragma unroll
            for (int nf = 0; nf < 4; ++nf)
                acc[mf][nf] = __builtin_amdgcn_mfma_f32_16x16x32_bf16(a[mf], b[nf], acc[mf][nf], 0, 0, 0);
    }
    #pragma unroll
    for (int mf = 0; mf < 4; ++mf)
        #pragma unroll
        for (int nf = 0; nf < 4; ++nf)
            #pragma unroll
            for (int r = 0; r < 4; ++r) {
                long pos = (long)mb * 128 + wm + mf * 16 + hig * 4 + r;
                int n = wn + nf * 16 + l15;
                out[pos * CIN + n] = acc[mf][nf][r];
            }
}

// ---------------------------------------------------------------------------
extern "C" void kernel_launch(void* const* d_in, const int* in_sizes, int n_in,
                              void* d_out, int out_size, void* d_ws, size_t ws_size,
                              hipStream_t stream)
{
    const float* z    = (const float*)d_in[0];
    const float* mask = (const float*)d_in[1];
    const float* lnw  = (const float*)d_in[2];
    const float* lnb  = (const float*)d_in[3];
    const float* wtri = (const float*)d_in[4];
    const float* wq   = (const float*)d_in[5];
    const float* wk   = (const float*)d_in[6];
    const float* wv   = (const float*)d_in[7];
    const float* wg   = (const float*)d_in[8];
    const float* wo   = (const float*)d_in[9];
    float* out = (float*)d_out;

    char* ws = (char*)d_ws;
    size_t off = 0;
    auto carve = [&](size_t bytes) -> void* {
        void* p = ws + off; off += (bytes + 255) & ~size_t(255); return p;
    };
    const size_t nelem = (size_t)NPOS * CIN;
    unsigned short* zn   = (unsigned short*)carve(nelem * 2);
    unsigned short* qb   = (unsigned short*)carve(nelem * 2);
    unsigned short* kb   = (unsigned short*)carve(nelem * 2);
    unsigned short* vb   = (unsigned short*)carve(nelem * 2);
    unsigned short* gb   = (unsigned short*)carve(nelem * 2);
    unsigned short* ogb  = (unsigned short*)carve(nelem * 2);
    unsigned short* trib = (unsigned short*)carve((size_t)NH * NPOS * 2);
    unsigned short* wcat = (unsigned short*)carve((size_t)5 * CIN * CIN * 2);
    unsigned short* wot  = (unsigned short*)carve((size_t)CIN * CIN * 2);
    (void)ws_size; (void)in_sizes; (void)n_in; (void)out_size;

    hipLaunchKernelGGL(ln_kernel, dim3(NPOS / 32), dim3(256), 0, stream,
                       z, lnw, lnb, zn);
    hipLaunchKernelGGL(wconv_kernel, dim3(6), dim3(256), 0, stream,
                       wq, wk, wv, wg, wtri, wo, wcat, wot);
    hipLaunchKernelGGL(proj_kernel, dim3(NPOS / 128), dim3(256), 0, stream,
                       zn, wcat, qb, kb, vb, gb, trib);
    hipLaunchKernelGGL(attn_kernel, dim3(NN * NH), dim3(256), 0, stream,
                       qb, kb, vb, gb, trib, mask, ogb);
    hipLaunchKernelGGL(out_gemm_kernel, dim3(NPOS / 128), dim3(256), 0, stream,
                       ogb, wot, out);
}

// Round 5
// 705.471 us; speedup vs baseline: 1.0627x; 1.0627x over previous
//
#include <hip/hip_runtime.h>
#include <hip/hip_bf16.h>

#define NN 384
#define CIN 128
#define NH 4
#define CH 32
#define NPOS (NN * NN)      // 147456
#define INFB 1e9f
#define LOG2E 1.4426950408889634f
#define QSCALE 0.17677669529663687f   // 1/sqrt(32)
#define QSB (QSCALE * LOG2E)

typedef float f32x4 __attribute__((ext_vector_type(4)));
typedef short bf16x8 __attribute__((ext_vector_type(8)));
typedef short bf16x4 __attribute__((ext_vector_type(4)));

__device__ __forceinline__ float bf2f(unsigned short u) {
    return __uint_as_float(((unsigned int)u) << 16);
}
__device__ __forceinline__ unsigned short f2bf(float f) {
    unsigned int u = __float_as_uint(f);
    u += 0x7fffu + ((u >> 16) & 1u);
    return (unsigned short)(u >> 16);
}
__device__ __forceinline__ unsigned int pack2bf(float a, float b) {
    return (unsigned int)f2bf(a) | ((unsigned int)f2bf(b) << 16);
}

// ---------------------------------------------------------------------------
// Kernel 1: LayerNorm -> zn bf16 [pos][128]
// ---------------------------------------------------------------------------
__global__ __launch_bounds__(256) void ln_kernel(
    const float* __restrict__ z, const float* __restrict__ lnw, const float* __restrict__ lnb,
    unsigned short* __restrict__ zn)
{
    const int t = threadIdx.x;
    const int l31 = t & 31;
    const f32x4 lw = *(const f32x4*)(lnw + l31 * 4);
    const f32x4 lb = *(const f32x4*)(lnb + l31 * 4);
    #pragma unroll
    for (int it = 0; it < 4; ++it) {
        long row = (long)blockIdx.x * 32 + it * 8 + (t >> 5);
        f32x4 v = *(const f32x4*)(z + row * CIN + l31 * 4);
        float s = v[0] + v[1] + v[2] + v[3];
        float q = v[0]*v[0] + v[1]*v[1] + v[2]*v[2] + v[3]*v[3];
        #pragma unroll
        for (int m2 = 1; m2 < 32; m2 <<= 1) { s += __shfl_xor(s, m2); q += __shfl_xor(q, m2); }
        float mu = s * (1.f / CIN);
        float rs = rsqrtf(q * (1.f / CIN) - mu * mu + 1e-5f);
        uint2 o;
        o.x = pack2bf((v[0]-mu)*rs*lw[0]+lb[0], (v[1]-mu)*rs*lw[1]+lb[1]);
        o.y = pack2bf((v[2]-mu)*rs*lw[2]+lb[2], (v[3]-mu)*rs*lw[3]+lb[3]);
        *(uint2*)(zn + row * CIN + l31 * 4) = o;
    }
}

// ---------------------------------------------------------------------------
// Kernel 2: weight convert (unchanged semantics)
// ---------------------------------------------------------------------------
__global__ __launch_bounds__(256) void wconv_kernel(
    const float* __restrict__ wq, const float* __restrict__ wk, const float* __restrict__ wv,
    const float* __restrict__ wg, const float* __restrict__ wtri, const float* __restrict__ wo,
    unsigned short* __restrict__ wcat, unsigned short* __restrict__ wot)
{
    const int m = blockIdx.x, t = threadIdx.x;
    for (int idx = t; idx < CIN * CIN; idx += 256) {
        int n = idx >> 7, k = idx & 127;
        if (m < 4) {
            const float* W = (m == 0) ? wq : (m == 1) ? wk : (m == 2) ? wv : wg;
            float s = (m == 0) ? QSB : 1.0f;
            wcat[m * CIN * CIN + idx] = f2bf(W[k * CIN + n] * s);
        } else if (m == 4) {
            wcat[4 * CIN * CIN + idx] = (n < NH) ? f2bf(wtri[k * NH + n] * LOG2E) : (unsigned short)0;
        } else {
            wot[idx] = f2bf(wo[k * CIN + n]);
        }
    }
}

// ---------------------------------------------------------------------------
// Kernel 3: fused 5-matrix projection GEMM.
// q/k/v/g stored [h][NPOS][32]; tri stored fragment-major:
// trib2[(((h*24+qt)*24+nf)*256) + hig*64 + l15*4 + r]  (q = qt*16+l15, k = nf*16+hig*4+r)
// ---------------------------------------------------------------------------
__global__ __launch_bounds__(256, 2) void proj_kernel(
    const unsigned short* __restrict__ zn, const unsigned short* __restrict__ wcat,
    unsigned short* __restrict__ qb, unsigned short* __restrict__ kb,
    unsigned short* __restrict__ vb, unsigned short* __restrict__ gb,
    unsigned short* __restrict__ trib2)
{
    __shared__ alignas(16) unsigned short lsA[128 * 128];
    __shared__ alignas(16) unsigned short lsB[128 * 128];
    const int t = threadIdx.x;
    const int mb = blockIdx.x;
    const int lane = t & 63, w = t >> 6, l15 = lane & 15, hig = lane >> 4;

    {   // stage A (swizzled)
        const unsigned short* Ag = zn + (long)mb * 16384;
        #pragma unroll
        for (int it = 0; it < 8; ++it) {
            int row = w * 32 + it * 4 + hig; int cb = l15 * 16;
            uint4 v = *(const uint4*)((const char*)Ag + row * 256 + cb);
            *(uint4*)((char*)lsA + row * 256 + (cb ^ ((row & 7) << 4))) = v;
        }
    }
    auto stageB = [&](int mat) {
        const unsigned short* Bg = wcat + mat * 16384;
        #pragma unroll
        for (int it = 0; it < 8; ++it) {
            int row = w * 32 + it * 4 + hig; int cb = l15 * 16;
            uint4 v = *(const uint4*)((const char*)Bg + row * 256 + cb);
            *(uint4*)((char*)lsB + row * 256 + (cb ^ ((row & 7) << 4))) = v;
        }
    };
    stageB(0);
    __syncthreads();

    const int wm = (w >> 1) * 64, wn = (w & 1) * 64;
    bf16x8 a[4][4];
    #pragma unroll
    for (int kk = 0; kk < 4; ++kk)
        #pragma unroll
        for (int mf = 0; mf < 4; ++mf) {
            int ra = wm + mf * 16 + l15;
            a[kk][mf] = *(const bf16x8*)((const char*)lsA + ra * 256 + ((kk * 64 + hig * 16) ^ ((ra & 7) << 4)));
        }

    for (int mat = 0;;) {
        f32x4 acc[4][4];
        #pragma unroll
        for (int i = 0; i < 4; ++i)
            #pragma unroll
            for (int j = 0; j < 4; ++j) acc[i][j] = (f32x4){0.f, 0.f, 0.f, 0.f};
        #pragma unroll
        for (int kk = 0; kk < 4; ++kk) {
            bf16x8 b[4];
            #pragma unroll
            for (int nf = 0; nf < 4; ++nf) {
                int rb = wn + nf * 16 + l15;
                b[nf] = *(const bf16x8*)((const char*)lsB + rb * 256 + ((kk * 64 + hig * 16) ^ ((rb & 7) << 4)));
            }
            #pragma unroll
            for (int mf = 0; mf < 4; ++mf)
                #pragma unroll
                for (int nf = 0; nf < 4; ++nf)
                    acc[mf][nf] = __builtin_amdgcn_mfma_f32_16x16x32_bf16(a[kk][mf], b[nf], acc[mf][nf], 0, 0, 0);
        }
        __syncthreads();                       // all waves done reading lsB
        if (mat < 4) stageB(mat + 1);          // overlap restage with stores

        if (mat < 4) {
            unsigned short* dst = (mat == 0) ? qb : (mat == 1) ? kb : (mat == 2) ? vb : gb;
            #pragma unroll
            for (int mf = 0; mf < 4; ++mf)
                #pragma unroll
                for (int nf = 0; nf < 4; ++nf)
                    #pragma unroll
                    for (int r = 0; r < 4; ++r) {
                        int pos = mb * 128 + wm + mf * 16 + hig * 4 + r;
                        int n = wn + nf * 16 + l15;
                        int hh = n >> 5, cc = n & 31;
                        float v = acc[mf][nf][r];
                        if (mat == 3) v = 1.f / (1.f + __expf(-v));
                        dst[((long)hh * NPOS + pos) * CH + cc] = f2bf(v);
                    }
        } else {
            if (wn == 0 && l15 < NH) {
                #pragma unroll
                for (int mf = 0; mf < 4; ++mf)
                    #pragma unroll
                    for (int r = 0; r < 4; ++r) {
                        int pos = mb * 128 + wm + mf * 16 + hig * 4 + r;
                        int q = pos / NN, k = pos - q * NN;
                        int qt = q >> 4, ql = q & 15;
                        int nfk = k >> 4, hk = (k >> 2) & 3, rk = k & 3;
                        trib2[(((long)l15 * 24 + qt) * 24 + nfk) * 256 + hk * 64 + ql * 4 + rk]
                            = f2bf(acc[mf][0][r]);
                    }
            }
        }
        if (mat == 4) break;
        ++mat;
        __syncthreads();                       // lsB(mat) ready
    }
}

// ---------------------------------------------------------------------------
// Kernel 4: attention. h-pinned XCD swizzle; [h][pos][32] operand layouts;
// fragment-major tri (coalesced C-init); swapped QK^T; chunked P LDS; fused gate.
// ---------------------------------------------------------------------------
__global__ __launch_bounds__(256, 2) void attn_kernel(
    const unsigned short* __restrict__ qb, const unsigned short* __restrict__ kb,
    const unsigned short* __restrict__ vb, const unsigned short* __restrict__ gb,
    const unsigned short* __restrict__ trib2, const float* __restrict__ mask,
    unsigned short* __restrict__ ogb)
{
    constexpr int KP = 40;    // K row pad (elems): 80 B rows
    constexpr int VP = 392;   // V^T row pad: 784 B rows
    __shared__ alignas(16) unsigned short Ks[NN * KP];        // 30720 B
    __shared__ alignas(16) unsigned short VTs[CH * VP];       // 25088 B
    __shared__ alignas(16) unsigned short Ps[4][2][16 * 64];  // 16384 B per-wave dbuf
    __shared__ float biasS[NN];

    const int t = threadIdx.x;
    const int bid = blockIdx.x;
    const int xcd = bid & 7, ord = bid >> 3;
    const int h = xcd >> 1;                      // h pinned: 2 XCDs per head
    const int i = (xcd & 1) * 192 + ord;
    const long hb = ((long)h * NPOS + (long)i * NN) * CH;

    {   // stage K (contiguous 64B rows), V^T (transpose), bias
        const uint4* ksrc = (const uint4*)(kb + hb);
        for (int idx = t; idx < NN * 4; idx += 256) {
            int row = idx >> 2, c8 = idx & 3;
            *(uint4*)&Ks[row * KP + c8 * 8] = ksrc[idx];
        }
        for (int idx = t; idx < CH * NN; idx += 256) {
            int n = idx >> 5, c = idx & 31;
            VTs[c * VP + n] = vb[hb + (long)n * CH + c];
        }
        for (int idx = t; idx < NN; idx += 256)
            biasS[idx] = (INFB * LOG2E) * (mask[(long)i * NN + idx] - 1.f);
    }
    __syncthreads();

    const int lane = t & 63, w = t >> 6, l15 = lane & 15, hig = lane >> 4;

    // V fragments -> registers (B-operand: lane&15 = out channel)
    bf16x8 bv[12][2];
    #pragma unroll
    for (int ks = 0; ks < 12; ++ks)
        #pragma unroll
        for (int hf = 0; hf < 2; ++hf) {
            int c = hf * 16 + l15;
            bv[ks][hf] = *(const bf16x8*)&VTs[c * VP + ks * 32 + hig * 8];
        }

    char* Pw = (char*)Ps[w];

    for (int mt = w; mt < NN / 16; mt += 4) {
        const int q0 = mt * 16;
        const bf16x8 aq = *(const bf16x8*)(qb + hb + (long)(q0 + l15) * CH + hig * 8);
        const unsigned short* trow = trib2 + ((long)(h * 24 + mt) * 24) * 256 + lane * 4;

        // QK^T with C-init = tri + mask-bias (exp2 domain); coalesced tri loads
        f32x4 acc[24];
        #pragma unroll
        for (int nf = 0; nf < 24; ++nf) {
            bf16x4 t4 = *(const bf16x4*)(trow + nf * 256);
            f32x4 ci;
            #pragma unroll
            for (int r = 0; r < 4; ++r)
                ci[r] = bf2f((unsigned short)t4[r]) + biasS[nf * 16 + hig * 4 + r];
            const bf16x8 ak = *(const bf16x8*)&Ks[(nf * 16 + l15) * KP + hig * 8];
            acc[nf] = __builtin_amdgcn_mfma_f32_16x16x32_bf16(ak, aq, ci, 0, 0, 0);
        }

        // softmax: q-row lane-local; combine hi-groups with 2 shuffles
        float mx = -3e38f;
        #pragma unroll
        for (int nf = 0; nf < 24; ++nf)
            #pragma unroll
            for (int r = 0; r < 4; ++r) mx = fmaxf(mx, acc[nf][r]);
        mx = fmaxf(mx, __shfl_xor(mx, 16));
        mx = fmaxf(mx, __shfl_xor(mx, 32));
        float sum = 0.f;
        #pragma unroll
        for (int nf = 0; nf < 24; ++nf)
            #pragma unroll
            for (int r = 0; r < 4; ++r) {
                float p = exp2f(acc[nf][r] - mx);
                acc[nf][r] = p; sum += p;
            }
        sum += __shfl_xor(sum, 16);
        sum += __shfl_xor(sum, 32);
        const float inv = 1.0f / sum;

        // PV: chunked P through per-wave swizzled LDS (dbuf), V from registers
        f32x4 o0 = {0.f,0.f,0.f,0.f}, o1 = {0.f,0.f,0.f,0.f};
        __builtin_amdgcn_s_setprio(1);
        #pragma unroll
        for (int ch = 0; ch < 6; ++ch) {
            char* Pb = Pw + (ch & 1) * 2048;
            #pragma unroll
            for (int nfl = 0; nfl < 4; ++nfl) {
                int nf = ch * 4 + nfl;
                uint2 wv;
                wv.x = pack2bf(acc[nf][0], acc[nf][1]);
                wv.y = pack2bf(acc[nf][2], acc[nf][3]);
                *(uint2*)(Pb + l15 * 128 + ((nfl * 32 + hig * 8) ^ ((l15 & 7) << 4))) = wv;
            }
            #pragma unroll
            for (int ksl = 0; ksl < 2; ++ksl) {
                int ks = ch * 2 + ksl;
                bf16x8 ap = *(const bf16x8*)(Pb + l15 * 128 + ((ksl * 64 + hig * 16) ^ ((l15 & 7) << 4)));
                o0 = __builtin_amdgcn_mfma_f32_16x16x32_bf16(ap, bv[ks][0], o0, 0, 0, 0);
                o1 = __builtin_amdgcn_mfma_f32_16x16x32_bf16(ap, bv[ks][1], o1, 0, 0, 0);
            }
        }
        __builtin_amdgcn_s_setprio(0);

        // epilogue: normalize, gate, store ([h][pos][32] => dense 64B rows)
        #pragma unroll
        for (int r = 0; r < 4; ++r) {
            float iv = __shfl(inv, hig * 4 + r);
            long qrow = (long)(q0 + hig * 4 + r);
            float g0 = bf2f(gb[hb + qrow * CH + l15]);
            float g1 = bf2f(gb[hb + qrow * CH + 16 + l15]);
            ogb[hb + qrow * CH + l15]      = f2bf(o0[r] * iv * g0);
            ogb[hb + qrow * CH + 16 + l15] = f2bf(o1[r] * iv * g1);
        }
    }
}

// ---------------------------------------------------------------------------
// Kernel 5: out = og @ wo^T (fp32). A gathered from 4 h-regions of [h][pos][32].
// ---------------------------------------------------------------------------
__global__ __launch_bounds__(256, 2) void out_gemm_kernel(
    const unsigned short* __restrict__ og, const unsigned short* __restrict__ wot,
    float* __restrict__ out)
{
    __shared__ alignas(16) unsigned short lsA[128 * 128];
    __shared__ alignas(16) unsigned short lsB[128 * 128];
    const int t = threadIdx.x;
    const int mb = blockIdx.x;
    const int lane = t & 63, w = t >> 6, l15 = lane & 15, hig = lane >> 4;

    {
        #pragma unroll
        for (int it = 0; it < 8; ++it) {
            int flat = it * 64 + lane;            // 0..511 per wave
            int rid = flat >> 4, cid = flat & 15;
            int row = w * 32 + rid;
            int hh = cid >> 2, c4 = cid & 3;
            uint4 va = *(const uint4*)(og + ((long)hh * NPOS + (long)mb * 128 + row) * CH + c4 * 8);
            uint4 vb4 = *(const uint4*)((const char*)wot + row * 256 + cid * 16);
            int cb = cid * 16;
            int sw = cb ^ ((row & 7) << 4);
            *(uint4*)((char*)lsA + row * 256 + sw) = va;
            *(uint4*)((char*)lsB + row * 256 + sw) = vb4;
        }
    }
    __syncthreads();

    const int wm = (w >> 1) * 64, wn = (w & 1) * 64;
    f32x4 acc[4][4];
    #pragma unroll
    for (int i = 0; i < 4; ++i)
        #pragma unroll
        for (int j = 0; j < 4; ++j) acc[i][j] = (f32x4){0.f, 0.f, 0.f, 0.f};
    #pragma unroll
    for (int kk = 0; kk < 4; ++kk) {
        bf16x8 a[4], b[4];
        #pragma unroll
        for (int f = 0; f < 4; ++f) {
            int ra = wm + f * 16 + l15;
            int rb = wn + f * 16 + l15;
            int c = kk * 64 + hig * 16;
            a[f] = *(const bf16x8*)((const char*)lsA + ra * 256 + (c ^ ((ra & 7) << 4)));
            b[f] = *(const bf16x8*)((const char*)lsB + rb * 256 + (c ^ ((rb & 7) << 4)));
        }
        #pragma unroll
        for (int mf = 0; mf < 4; ++mf)
            #pragma unroll
            for (int nf = 0; nf < 4; ++nf)
                acc[mf][nf] = __builtin_amdgcn_mfma_f32_16x16x32_bf16(a[mf], b[nf], acc[mf][nf], 0, 0, 0);
    }
    #pragma unroll
    for (int mf = 0; mf < 4; ++mf)
        #pragma unroll
        for (int nf = 0; nf < 4; ++nf)
            #pragma unroll
            for (int r = 0; r < 4; ++r) {
                long pos = (long)mb * 128 + wm + mf * 16 + hig * 4 + r;
                int n = wn + nf * 16 + l15;
                out[pos * CIN + n] = acc[mf][nf][r];
            }
}

// ---------------------------------------------------------------------------
extern "C" void kernel_launch(void* const* d_in, const int* in_sizes, int n_in,
                              void* d_out, int out_size, void* d_ws, size_t ws_size,
                              hipStream_t stream)
{
    const float* z    = (const float*)d_in[0];
    const float* mask = (const float*)d_in[1];
    const float* lnw  = (const float*)d_in[2];
    const float* lnb  = (const float*)d_in[3];
    const float* wtri = (const float*)d_in[4];
    const float* wq   = (const float*)d_in[5];
    const float* wk   = (const float*)d_in[6];
    const float* wv   = (const float*)d_in[7];
    const float* wg   = (const float*)d_in[8];
    const float* wo   = (const float*)d_in[9];
    float* out = (float*)d_out;

    char* ws = (char*)d_ws;
    size_t off = 0;
    auto carve = [&](size_t bytes) -> void* {
        void* p = ws + off; off += (bytes + 255) & ~size_t(255); return p;
    };
    const size_t nelem = (size_t)NPOS * CIN;
    unsigned short* zn    = (unsigned short*)carve(nelem * 2);
    unsigned short* qb    = (unsigned short*)carve(nelem * 2);
    unsigned short* kb    = (unsigned short*)carve(nelem * 2);
    unsigned short* vb    = (unsigned short*)carve(nelem * 2);
    unsigned short* gb    = (unsigned short*)carve(nelem * 2);
    unsigned short* ogb   = (unsigned short*)carve(nelem * 2);
    unsigned short* trib2 = (unsigned short*)carve((size_t)NH * NPOS * 2);
    unsigned short* wcat  = (unsigned short*)carve((size_t)5 * CIN * CIN * 2);
    unsigned short* wot   = (unsigned short*)carve((size_t)CIN * CIN * 2);
    (void)ws_size; (void)in_sizes; (void)n_in; (void)out_size;

    hipLaunchKernelGGL(ln_kernel, dim3(NPOS / 32), dim3(256), 0, stream,
                       z, lnw, lnb, zn);
    hipLaunchKernelGGL(wconv_kernel, dim3(6), dim3(256), 0, stream,
                       wq, wk, wv, wg, wtri, wo, wcat, wot);
    hipLaunchKernelGGL(proj_kernel, dim3(NPOS / 128), dim3(256), 0, stream,
                       zn, wcat, qb, kb, vb, gb, trib2);
    hipLaunchKernelGGL(attn_kernel, dim3(NN * NH), dim3(256), 0, stream,
                       qb, kb, vb, gb, trib2, mask, ogb);
    hipLaunchKernelGGL(out_gemm_kernel, dim3(NPOS / 128), dim3(256), 0, stream,
                       ogb, wot, out);
}